// Round 1
// baseline (81.042 us; speedup 1.0000x reference)
//
#include <hip/hip_runtime.h>

// Problem constants (match reference setup_inputs / globals)
#define BB   64          // batch
#define DD   131072      // feature dim
#define KK   5           // top-k
#define NBLK 8           // partial blocks per row
#define SEG  (DD / NBLK) // 16384 elements per partial block
#define TPB  256

#define NEG_INF (-__builtin_inff())

// ranking: higher value wins; tie -> lower index wins (matches lax.top_k)
__device__ __forceinline__ bool vi_gt(float av, int ai, float bv, int bi) {
    return (av > bv) || (av == bv && ai < bi);
}

__device__ __forceinline__ void insert5(float (&tv)[KK], int (&ti)[KK], float v, int idx) {
    if (v < tv[KK - 1]) return;                       // fast reject (common case)
    if (!vi_gt(v, idx, tv[KK - 1], ti[KK - 1])) return;
    tv[KK - 1] = v; ti[KK - 1] = idx;
#pragma unroll
    for (int k = KK - 1; k > 0; --k) {
        bool sw = vi_gt(tv[k], ti[k], tv[k - 1], ti[k - 1]);
        if (sw) {
            float fv = tv[k]; tv[k] = tv[k - 1]; tv[k - 1] = fv;
            int   fi = ti[k]; ti[k] = ti[k - 1]; ti[k - 1] = fi;
        }
    }
}

// Kernel A: per (row, segment) partial top-5.
// grid = BB*NBLK blocks, TPB threads. Coalesced float4 reads.
__global__ __launch_bounds__(TPB) void topk_partial(const float* __restrict__ sim,
                                                    float* __restrict__ wsv,
                                                    int* __restrict__ wsi) {
    const int blk = blockIdx.x;
    const int row = blk >> 3;   // / NBLK
    const int seg = blk & 7;    // % NBLK
    const int tid = threadIdx.x;

    const float4* b4 = reinterpret_cast<const float4*>(
        sim + (size_t)row * DD + (size_t)seg * SEG);

    float tv[KK]; int ti[KK];
#pragma unroll
    for (int k = 0; k < KK; ++k) { tv[k] = NEG_INF; ti[k] = 0x7fffffff; }

#pragma unroll
    for (int it = 0; it < SEG / 4 / TPB; ++it) {   // 16 iterations
        const int o4 = it * TPB + tid;
        const float4 x = b4[o4];
        const int gi = seg * SEG + (o4 << 2);      // index within the row
        insert5(tv, ti, x.x, gi + 0);
        insert5(tv, ti, x.y, gi + 1);
        insert5(tv, ti, x.z, gi + 2);
        insert5(tv, ti, x.w, gi + 3);
    }

    // dump per-thread candidates to LDS, then 5 rounds of block argmax
    __shared__ float lv[TPB * KK];
    __shared__ int   li[TPB * KK];
#pragma unroll
    for (int k = 0; k < KK; ++k) { lv[tid * KK + k] = tv[k]; li[tid * KK + k] = ti[k]; }
    __syncthreads();

    __shared__ float wv[TPB / 64];
    __shared__ int   wi[TPB / 64];
    __shared__ int   wslot[TPB / 64];
    __shared__ float ov[KK];
    __shared__ int   oi[KK];

    for (int k = 0; k < KK; ++k) {
        float bv = NEG_INF; int bi = 0x7fffffff; int bs = 0;
#pragma unroll
        for (int j = 0; j < KK; ++j) {
            const int s = tid * KK + j;
            const float v = lv[s]; const int g = li[s];
            if (vi_gt(v, g, bv, bi)) { bv = v; bi = g; bs = s; }
        }
        // 64-lane wave argmax (value, index, slot)
#pragma unroll
        for (int off = 32; off > 0; off >>= 1) {
            const float xv = __shfl_xor(bv, off);
            const int   xi = __shfl_xor(bi, off);
            const int   xs = __shfl_xor(bs, off);
            if (vi_gt(xv, xi, bv, bi)) { bv = xv; bi = xi; bs = xs; }
        }
        const int lane = tid & 63, wid = tid >> 6;
        if (lane == 0) { wv[wid] = bv; wi[wid] = bi; wslot[wid] = bs; }
        __syncthreads();
        if (tid == 0) {
            float fv = wv[0]; int fi = wi[0]; int fs = wslot[0];
#pragma unroll
            for (int w = 1; w < TPB / 64; ++w)
                if (vi_gt(wv[w], wi[w], fv, fi)) { fv = wv[w]; fi = wi[w]; fs = wslot[w]; }
            ov[k] = fv; oi[k] = fi;
            lv[fs] = NEG_INF;    // invalidate chosen slot
        }
        __syncthreads();
    }

    if (tid < KK) {
        wsv[blk * KK + tid] = ov[tid];
        wsi[blk * KK + tid] = oi[tid];
    }
}

// Kernel B: 64 threads, thread r merges row r's NBLK*5 candidates,
// writes indices (as float) and scatters the one-hot 1.0f values.
__global__ void topk_final(const float* __restrict__ wsv,
                           const int* __restrict__ wsi,
                           float* __restrict__ out) {
    const int r = threadIdx.x;   // 0..63 (one block of 64 threads)
    __shared__ float sv[BB][NBLK * KK];
    __shared__ int   si[BB][NBLK * KK];
    for (int s = 0; s < NBLK * KK; ++s) {
        sv[r][s] = wsv[r * NBLK * KK + s];
        si[r][s] = wsi[r * NBLK * KK + s];
    }
#pragma unroll
    for (int k = 0; k < KK; ++k) {
        float bv = NEG_INF; int bi = 0x7fffffff; int bs = 0;
        for (int s = 0; s < NBLK * KK; ++s) {
            const float v = sv[r][s]; const int g = si[r][s];
            if (vi_gt(v, g, bv, bi)) { bv = v; bi = g; bs = s; }
        }
        sv[r][bs] = NEG_INF;
        // hard_indices chunk: first BB*KK floats
        out[r * KK + k] = (float)bi;
        // soft_weights chunk: forward value of straight-through == one-hot
        out[(size_t)BB * KK + (size_t)(r * KK + k) * DD + (size_t)bi] = 1.0f;
    }
}

extern "C" void kernel_launch(void* const* d_in, const int* in_sizes, int n_in,
                              void* d_out, int out_size, void* d_ws, size_t ws_size,
                              hipStream_t stream) {
    const float* sim = (const float*)d_in[0];
    float* out = (float*)d_out;

    // workspace layout: [BB*NBLK*KK floats][BB*NBLK*KK ints] = 20.5 KB
    float* wsv = (float*)d_ws;
    int*   wsi = (int*)((char*)d_ws + (size_t)BB * NBLK * KK * sizeof(float));

    // zero the entire output (soft_weights are one-hot; indices overwritten below)
    hipMemsetAsync(d_out, 0, (size_t)out_size * sizeof(float), stream);

    hipLaunchKernelGGL(topk_partial, dim3(BB * NBLK), dim3(TPB), 0, stream,
                       sim, wsv, wsi);
    hipLaunchKernelGGL(topk_final, dim3(1), dim3(64), 0, stream,
                       wsv, wsi, out);
}